// Round 1
// baseline (189.301 us; speedup 1.0000x reference)
//
#include <hip/hip_runtime.h>
#include <hip/hip_bf16.h>

#define S_LEN 2048
#define D_DIM 64
#define NH    12
#define NB    2
#define SCALE 0.125f   // 1/sqrt(64)

typedef __attribute__((ext_vector_type(8))) short short8;
typedef __attribute__((ext_vector_type(4))) float f32x4;

static __device__ inline unsigned short f2bf(float f) {
    union { float f; unsigned u; } cv; cv.f = f;
    unsigned u = cv.u;
    unsigned r = (u + 0x7fffu + ((u >> 16) & 1u)) >> 16;  // RNE
    return (unsigned short)r;
}

__global__ __launch_bounds__(256, 3) void attn_fwd(
    const float* __restrict__ q, const float* __restrict__ k,
    const float* __restrict__ v, const int* __restrict__ mask,
    float* __restrict__ out)
{
    // LDS: K tile (64x64 bf16, row=key, 128B rows, XOR-swizzled)
    //      Vt tile (64x64 bf16, row=d,  128B rows, XOR-swizzled)
    //      P tiles (4 waves x 16x64 bf16, row=q, XOR-swizzled)
    __shared__ __align__(16) unsigned short sK[4096];
    __shared__ __align__(16) unsigned short sVt[4096];
    __shared__ __align__(16) unsigned short sP[4096];

    const int tid  = threadIdx.x;
    const int wave = tid >> 6;
    const int lane = tid & 63;
    const int l16  = lane & 15;
    const int lhi  = lane >> 4;     // 0..3

    const int bh = blockIdx.y;      // 0..23
    const int b  = bh / NH;
    const int q0 = blockIdx.x * 64;
    const int qw = q0 + wave * 16;  // this wave's 16 query rows

    const float* qbase = q + (size_t)bh * S_LEN * D_DIM;
    const float* kbase = k + (size_t)bh * S_LEN * D_DIM;
    const float* vbase = v + (size_t)bh * S_LEN * D_DIM;
    const int*   mbase = mask + (size_t)b * S_LEN * S_LEN;

    // ---- Q fragments in registers: A[row=l16][k = ks*32 + lhi*8 + j] ----
    short8 aq[2];
#pragma unroll
    for (int ks = 0; ks < 2; ++ks) {
        const float* src = qbase + (size_t)(qw + l16) * D_DIM + ks * 32 + lhi * 8;
        float4 f0 = *(const float4*)(src);
        float4 f1 = *(const float4*)(src + 4);
        short8 a;
        a[0] = (short)f2bf(f0.x); a[1] = (short)f2bf(f0.y);
        a[2] = (short)f2bf(f0.z); a[3] = (short)f2bf(f0.w);
        a[4] = (short)f2bf(f1.x); a[5] = (short)f2bf(f1.y);
        a[6] = (short)f2bf(f1.z); a[7] = (short)f2bf(f1.w);
        aq[ks] = a;
    }

    f32x4 o[4];
#pragma unroll
    for (int dt = 0; dt < 4; ++dt) o[dt] = (f32x4){0.f, 0.f, 0.f, 0.f};
    float mrow[4] = {-1e30f, -1e30f, -1e30f, -1e30f};
    float lrow[4] = {0.f, 0.f, 0.f, 0.f};

    unsigned short* pw = sP + wave * 1024;   // 16x64 bf16 wave-private

    for (int kv0 = 0; kv0 < S_LEN; kv0 += 64) {
        __syncthreads();   // previous iteration's reads of sK/sVt are done

        // ---- stage K tile: sK[key][d], swizzled ----
        for (int i = tid; i < 1024; i += 256) {
            int row = i >> 4, c4 = i & 15, d = c4 * 4;
            float4 f = *(const float4*)(kbase + (size_t)(kv0 + row) * D_DIM + d);
            unsigned p0 = (unsigned)f2bf(f.x) | ((unsigned)f2bf(f.y) << 16);
            unsigned p1 = (unsigned)f2bf(f.z) | ((unsigned)f2bf(f.w) << 16);
            int byte = row * 128 + ((d * 2) ^ ((row & 7) << 4));
            *(uint2*)((char*)sK + byte) = make_uint2(p0, p1);
        }
        // ---- stage V transposed: sVt[d][key], swizzled ----
        for (int i = tid; i < 1024; i += 256) {
            int row = i >> 4, c4 = i & 15, d = c4 * 4;
            float4 f = *(const float4*)(vbase + (size_t)(kv0 + row) * D_DIM + d);
            float ff[4] = {f.x, f.y, f.z, f.w};
#pragma unroll
            for (int jj = 0; jj < 4; ++jj) {
                int dd = d + jj;
                int byte = dd * 128 + ((row * 2) ^ ((dd & 7) << 4));
                *(unsigned short*)((char*)sVt + byte) = f2bf(ff[jj]);
            }
        }
        __syncthreads();

        // ---- QK^T: 4 col-tiles x 2 k-steps ----
        f32x4 sc[4];
#pragma unroll
        for (int t = 0; t < 4; ++t) sc[t] = (f32x4){0.f, 0.f, 0.f, 0.f};
#pragma unroll
        for (int ks = 0; ks < 2; ++ks) {
#pragma unroll
            for (int t = 0; t < 4; ++t) {
                int row = t * 16 + l16;
                int byte = row * 128 + ((ks * 64 + lhi * 16) ^ ((row & 7) << 4));
                short8 bk = *(const short8*)((const char*)sK + byte);
                sc[t] = __builtin_amdgcn_mfma_f32_16x16x32_bf16(aq[ks], bk, sc[t], 0, 0, 0);
            }
        }

        // ---- scale + mask + online softmax ----
        float pm[4] = {-1e30f, -1e30f, -1e30f, -1e30f};
#pragma unroll
        for (int t = 0; t < 4; ++t) {
            int key = kv0 + t * 16 + l16;
#pragma unroll
            for (int r = 0; r < 4; ++r) {
                int qrow = qw + lhi * 4 + r;
                float s = sc[t][r] * SCALE;
                int mv = mbase[(size_t)qrow * S_LEN + key];
                s = mv ? s : -1e9f;
                sc[t][r] = s;
                pm[r] = fmaxf(pm[r], s);
            }
        }
#pragma unroll
        for (int off = 8; off; off >>= 1)
#pragma unroll
            for (int r = 0; r < 4; ++r)
                pm[r] = fmaxf(pm[r], __shfl_xor(pm[r], off, 16));

        float fsc[4], rs[4];
#pragma unroll
        for (int r = 0; r < 4; ++r) {
            float mn = fmaxf(mrow[r], pm[r]);
            fsc[r] = __expf(mrow[r] - mn);
            mrow[r] = mn;
            rs[r] = 0.f;
        }
#pragma unroll
        for (int t = 0; t < 4; ++t)
#pragma unroll
            for (int r = 0; r < 4; ++r) {
                float p = __expf(sc[t][r] - mrow[r]);
                sc[t][r] = p;
                rs[r] += p;
            }
#pragma unroll
        for (int off = 8; off; off >>= 1)
#pragma unroll
            for (int r = 0; r < 4; ++r)
                rs[r] += __shfl_xor(rs[r], off, 16);
#pragma unroll
        for (int r = 0; r < 4; ++r)
            lrow[r] = lrow[r] * fsc[r] + rs[r];
#pragma unroll
        for (int dt = 0; dt < 4; ++dt)
#pragma unroll
            for (int r = 0; r < 4; ++r)
                o[dt][r] *= fsc[r];

        // ---- P -> LDS (bf16, A-layout source) ----
#pragma unroll
        for (int t = 0; t < 4; ++t)
#pragma unroll
            for (int r = 0; r < 4; ++r) {
                int row = lhi * 4 + r;
                int byte = row * 128 + (((t * 16 + l16) * 2) ^ ((row & 7) << 4));
                *(unsigned short*)((char*)pw + byte) = f2bf(sc[t][r]);
            }

        // ---- PV: o += P @ V ----
#pragma unroll
        for (int ks = 0; ks < 2; ++ks) {
            int prow = l16;
            int pbyte = prow * 128 + ((ks * 64 + lhi * 16) ^ ((prow & 7) << 4));
            short8 pa = *(const short8*)((const char*)pw + pbyte);
#pragma unroll
            for (int dt = 0; dt < 4; ++dt) {
                int drow = dt * 16 + l16;
                int vbyte = drow * 128 + ((ks * 64 + lhi * 16) ^ ((drow & 7) << 4));
                short8 bv = *(const short8*)((const char*)sVt + vbyte);
                o[dt] = __builtin_amdgcn_mfma_f32_16x16x32_bf16(pa, bv, o[dt], 0, 0, 0);
            }
        }
    }

    // ---- epilogue: normalize and store fp32 ----
    float inv[4];
#pragma unroll
    for (int r = 0; r < 4; ++r) inv[r] = 1.0f / lrow[r];
#pragma unroll
    for (int dt = 0; dt < 4; ++dt)
#pragma unroll
        for (int r = 0; r < 4; ++r) {
            int qrow = qw + lhi * 4 + r;
            int dcol = dt * 16 + l16;
            out[(size_t)bh * S_LEN * D_DIM + (size_t)qrow * D_DIM + dcol] = o[dt][r] * inv[r];
        }
}

extern "C" void kernel_launch(void* const* d_in, const int* in_sizes, int n_in,
                              void* d_out, int out_size, void* d_ws, size_t ws_size,
                              hipStream_t stream) {
    const float* q   = (const float*)d_in[0];
    const float* k   = (const float*)d_in[1];
    const float* v   = (const float*)d_in[2];
    const int* mask  = (const int*)d_in[3];
    float* out = (float*)d_out;
    dim3 grid(S_LEN / 64, NB * NH);
    attn_fwd<<<grid, dim3(256), 0, stream>>>(q, k, v, mask, out);
}

// Round 2
// 125.711 us; speedup vs baseline: 1.5058x; 1.5058x over previous
//
#include <hip/hip_runtime.h>
#include <hip/hip_bf16.h>

#define S_LEN 2048
#define D_DIM 64
#define NH    12
#define NB    2

typedef __attribute__((ext_vector_type(8))) short short8;
typedef __attribute__((ext_vector_type(4))) float f32x4;

static __device__ inline unsigned short bfbits(float f) {
    __hip_bfloat16 h = __float2bfloat16(f);
    return *reinterpret_cast<unsigned short*>(&h);
}

__global__ __launch_bounds__(256, 3) void attn_fwd(
    const float* __restrict__ q, const float* __restrict__ k,
    const float* __restrict__ v, const int* __restrict__ mask,
    float* __restrict__ out)
{
    // sK : 64 keys x 64 d, bf16, 128B rows, XOR-swizzled
    // sVt: 64 d x 64 keys, bf16, 128B rows, XOR-swizzled
    // sP : per-wave 16 q x 64 keys, bf16, XOR-swizzled
    __shared__ __align__(16) unsigned short sK[4096];
    __shared__ __align__(16) unsigned short sVt[4096];
    __shared__ __align__(16) unsigned short sP[4096];

    const int tid  = threadIdx.x;
    const int wave = tid >> 6;
    const int lane = tid & 63;
    const int l16  = lane & 15;
    const int lhi  = lane >> 4;     // 0..3

    const int bh = blockIdx.y;      // 0..23
    const int b  = bh / NH;
    const int q0 = blockIdx.x * 64;
    const int qw = q0 + wave * 16;  // wave's 16 query rows
    const int qq = qw + l16;        // this lane's q row (softmax owner)

    const float* qbase = q + (size_t)bh * S_LEN * D_DIM;
    const float* kbase = k + (size_t)bh * S_LEN * D_DIM;
    const float* vbase = v + (size_t)bh * S_LEN * D_DIM;
    const int*   mbase = mask + (size_t)b * S_LEN * S_LEN;

    // fold 1/sqrt(64) and log2(e) into Q so softmax uses exp2 directly
    const float PRE = 0.125f * 1.44269504088896f;

    // ---- Q fragments (B-operand of swapped QK): b[j] = Q[q=l16][ks*32+lhi*8+j]
    short8 bq[2];
#pragma unroll
    for (int ks = 0; ks < 2; ++ks) {
        const float* src = qbase + (size_t)qq * D_DIM + ks * 32 + lhi * 8;
        float4 f0 = *(const float4*)(src);
        float4 f1 = *(const float4*)(src + 4);
        short8 a;
        a[0] = (short)bfbits(f0.x * PRE); a[1] = (short)bfbits(f0.y * PRE);
        a[2] = (short)bfbits(f0.z * PRE); a[3] = (short)bfbits(f0.w * PRE);
        a[4] = (short)bfbits(f1.x * PRE); a[5] = (short)bfbits(f1.y * PRE);
        a[6] = (short)bfbits(f1.z * PRE); a[7] = (short)bfbits(f1.w * PRE);
        bq[ks] = a;
    }

    f32x4 o[4];
#pragma unroll
    for (int dt = 0; dt < 4; ++dt) o[dt] = (f32x4){0.f, 0.f, 0.f, 0.f};
    float mrun = -1e30f;
    float lrun = 0.f;

    unsigned short* pw = sP + wave * 1024;

    // staging geometry: i = tid + 256*s -> row = i>>4, d = (i&15)*4 (thread-invariant)
    int srow[4], sd[4];
#pragma unroll
    for (int s = 0; s < 4; ++s) { int i = tid + 256 * s; srow[s] = i >> 4; sd[s] = (i & 15) * 4; }

    // ---- prologue: prefetch tile 0 into registers ----
    float4 kreg[4], vreg[4];
#pragma unroll
    for (int s = 0; s < 4; ++s) {
        kreg[s] = *(const float4*)(kbase + (size_t)srow[s] * D_DIM + sd[s]);
        vreg[s] = *(const float4*)(vbase + (size_t)srow[s] * D_DIM + sd[s]);
    }

    for (int kv0 = 0; kv0 < S_LEN; kv0 += 64) {
        __syncthreads();   // prev tile's LDS reads complete

        // ---- regs -> LDS ----
#pragma unroll
        for (int s = 0; s < 4; ++s) {
            unsigned p0 = (unsigned)bfbits(kreg[s].x) | ((unsigned)bfbits(kreg[s].y) << 16);
            unsigned p1 = (unsigned)bfbits(kreg[s].z) | ((unsigned)bfbits(kreg[s].w) << 16);
            int byte = srow[s] * 128 + ((sd[s] * 2) ^ ((srow[s] & 7) << 4));
            *(uint2*)((char*)sK + byte) = make_uint2(p0, p1);
        }
#pragma unroll
        for (int s = 0; s < 4; ++s) {
            float ff[4] = {vreg[s].x, vreg[s].y, vreg[s].z, vreg[s].w};
#pragma unroll
            for (int jj = 0; jj < 4; ++jj) {
                int dd = sd[s] + jj;
                int byte = dd * 128 + ((srow[s] * 2) ^ ((dd & 7) << 4));
                *(unsigned short*)((char*)sVt + byte) = bfbits(ff[jj]);
            }
        }
        __syncthreads();   // tile ready

        // ---- prefetch next tile (overlaps all compute below) ----
        if (kv0 + 64 < S_LEN) {
#pragma unroll
            for (int s = 0; s < 4; ++s) {
                kreg[s] = *(const float4*)(kbase + (size_t)(kv0 + 64 + srow[s]) * D_DIM + sd[s]);
                vreg[s] = *(const float4*)(vbase + (size_t)(kv0 + 64 + srow[s]) * D_DIM + sd[s]);
            }
        }

        // ---- mask for this tile: lane's q row, keys kv0 + t*16 + lhi*4 + r ----
        int4 mreg[4];
#pragma unroll
        for (int t = 0; t < 4; ++t)
            mreg[t] = *(const int4*)(mbase + (size_t)qq * S_LEN + kv0 + t * 16 + lhi * 4);

        // ---- swapped QK^T: sc[t][r] = S[key = kv0+t*16+lhi*4+r][q = l16] ----
        f32x4 sc[4];
#pragma unroll
        for (int t = 0; t < 4; ++t) sc[t] = (f32x4){0.f, 0.f, 0.f, 0.f};
#pragma unroll
        for (int ks = 0; ks < 2; ++ks) {
#pragma unroll
            for (int t = 0; t < 4; ++t) {
                int row = t * 16 + l16;
                int byte = row * 128 + ((ks * 64 + lhi * 16) ^ ((row & 7) << 4));
                short8 ak = *(const short8*)((const char*)sK + byte);
                sc[t] = __builtin_amdgcn_mfma_f32_16x16x32_bf16(ak, bq[ks], sc[t], 0, 0, 0);
            }
        }

        // ---- mask + online softmax (lane-local q) ----
        float pm = -1e30f;
#pragma unroll
        for (int t = 0; t < 4; ++t)
#pragma unroll
            for (int r = 0; r < 4; ++r) {
                float s = sc[t][r];
                int mv = ((const int*)&mreg[t])[r];
                s = mv ? s : -1e9f;
                sc[t][r] = s;
                pm = fmaxf(pm, s);
            }
        pm = fmaxf(pm, __shfl_xor(pm, 16));
        pm = fmaxf(pm, __shfl_xor(pm, 32));

        float mnew = fmaxf(mrun, pm);
        float fsc = exp2f(mrun - mnew);
        mrun = mnew;
        float rs = 0.f;
#pragma unroll
        for (int t = 0; t < 4; ++t)
#pragma unroll
            for (int r = 0; r < 4; ++r) {
                float p = exp2f(sc[t][r] - mnew);
                sc[t][r] = p;
                rs += p;
            }
        rs += __shfl_xor(rs, 16);
        rs += __shfl_xor(rs, 32);
        lrun = lrun * fsc + rs;

        float fr[4];
#pragma unroll
        for (int r = 0; r < 4; ++r) fr[r] = __shfl(fsc, lhi * 4 + r);
#pragma unroll
        for (int dt = 0; dt < 4; ++dt)
#pragma unroll
            for (int r = 0; r < 4; ++r) o[dt][r] *= fr[r];

        // ---- P -> LDS: row = q (l16), cols t*16+lhi*4+r, vectorized uint2 ----
#pragma unroll
        for (int t = 0; t < 4; ++t) {
            unsigned p0 = (unsigned)bfbits(sc[t][0]) | ((unsigned)bfbits(sc[t][1]) << 16);
            unsigned p1 = (unsigned)bfbits(sc[t][2]) | ((unsigned)bfbits(sc[t][3]) << 16);
            int byte = l16 * 128 + (((t * 16 + lhi * 4) * 2) ^ ((l16 & 7) << 4));
            *(uint2*)((char*)pw + byte) = make_uint2(p0, p1);
        }

        // ---- PV: o += P @ V ----
#pragma unroll
        for (int ks = 0; ks < 2; ++ks) {
            int pbyte = l16 * 128 + ((ks * 64 + lhi * 16) ^ ((l16 & 7) << 4));
            short8 pa = *(const short8*)((const char*)pw + pbyte);
#pragma unroll
            for (int dt = 0; dt < 4; ++dt) {
                int drow = dt * 16 + l16;
                int vbyte = drow * 128 + ((ks * 64 + lhi * 16) ^ ((drow & 7) << 4));
                short8 bv = *(const short8*)((const char*)sVt + vbyte);
                o[dt] = __builtin_amdgcn_mfma_f32_16x16x32_bf16(pa, bv, o[dt], 0, 0, 0);
            }
        }
    }

    // ---- epilogue ----
    float invl = 1.0f / lrun;
    float ir[4];
#pragma unroll
    for (int r = 0; r < 4; ++r) ir[r] = __shfl(invl, lhi * 4 + r);
#pragma unroll
    for (int dt = 0; dt < 4; ++dt)
#pragma unroll
        for (int r = 0; r < 4; ++r) {
            int qrow = qw + lhi * 4 + r;
            int dcol = dt * 16 + l16;
            out[(size_t)bh * S_LEN * D_DIM + (size_t)qrow * D_DIM + dcol] = o[dt][r] * ir[r];
        }
}

extern "C" void kernel_launch(void* const* d_in, const int* in_sizes, int n_in,
                              void* d_out, int out_size, void* d_ws, size_t ws_size,
                              hipStream_t stream) {
    const float* q   = (const float*)d_in[0];
    const float* k   = (const float*)d_in[1];
    const float* v   = (const float*)d_in[2];
    const int* mask  = (const int*)d_in[3];
    float* out = (float*)d_out;
    dim3 grid(S_LEN / 64, NB * NH);
    attn_fwd<<<grid, dim3(256), 0, stream>>>(q, k, v, mask, out);
}